// Round 1
// baseline (204.469 us; speedup 1.0000x reference)
//
#include <hip/hip_runtime.h>
#include <math.h>

// CapsuleLayer dynamic routing, fp32, MI355X (gfx950).
// B=64, IN_CAPS=2048, IN_DIM=8, OUT_CAPS=32, OUT_DIM=16, 3 routing iters.
//
// b_ij after r updates = u_hat_i . (v0+...+v_{r-1}) (b starts at 0), so no
// u_hat materialization: each pass recomputes u_hat from W via LDS staging.
//
// R2 -> R3: R2's pass was LDS-issue-bound (per CU-iter: ~3.4k cyc LDS pipe vs
// ~1.4k VALU): every wave re-read the full 16KB W tile (4 b's/wave), softmax
// used 24 LDS shuffle ops/iter, staging used ds_write_b128. Now:
//  - 128-thread blocks, 8 b's per wave: W ds_read count per pass halves.
//  - W staged with global_load_lds (no VGPR round trip, no ds_writes) into an
//    identity layout with XOR(o) chunk swizzle: source stays coalesced
//    (permutation within each 512B row), hot ds_read_b128 is conflict-free
//    (bank-quad occupancy uniform).
//  - softmax butterfly xor1/2 via DPP quad_perm, xor4/8 via row_ror (VALU
//    pipe); only xor16/xor32 remain LDS shuffles (6 -> 2 LDS ops per n).
//  - caps_reduce: 512 blocks (was 128 = 0.5 blk/CU); wave w sums stripes
//    k===w (mod 4) coalesced, LDS combine + in-wave squash.

#define IC 2048
#define ID 8
#define OC 32
#define OD 16
#define B_N 64
#define S_ELEMS (B_N * OC * OD)   // 32768
#define IB 16                     // i's per block
#define ISTR (IC / IB)            // 128 i-stripes
#define BPB 16                    // b's per block (8 per wave)
#define BG (B_N / BPB)            // 4 b-groups

// async 16B global->LDS (direct, no VGPR round trip)
__device__ __forceinline__ void gll16(const float4* g, float4* l)
{
    __builtin_amdgcn_global_load_lds(
        (const __attribute__((address_space(1))) void*)g,
        (__attribute__((address_space(3))) void*)l,
        16, 0, 0);
}

// x + dpp_perm(x) on the VALU pipe (no LDS traffic)
template <int CTRL>
__device__ __forceinline__ float dpp_add(float x)
{
    union { float f; int i; } a, b;
    a.f = x;
    b.i = __builtin_amdgcn_update_dpp(0, a.i, CTRL, 0xF, 0xF, true);
    return x + b.f;
}

// W tile i is 1024 float4 "chunks"; global chunk f = (o*16 + j)*2 + dq.
// LDS layout: row o (32 chunks), chunk slot = (j*2+dq) ^ o.  Staging dest is
// linear D = s*128+tid; the matching pre-swizzled source is
//   f(D) = (D>>5)*32 + ((D&31) ^ (D>>5)).
// Hot read, fixed (jj,dq): lanes (o,jh) hit slot ((jh*16+jj*2+dq)^o) in row o
// -> slot%8 uniform over lanes -> conflict-free b128.

template <int FIRST>
__launch_bounds__(128, 1)
__global__ void caps_pass(const float* __restrict__ Wg,
                          const float* __restrict__ xg,
                          const float* __restrict__ vs,
                          float* __restrict__ part)
{
    __shared__ float4 Wl[2][1024];      // 32 KB, double-buffered W tile
    __shared__ float4 xsh[2][BPB * 2];  // 1 KB, x fragments

    const int tid  = threadIdx.x;
    const int lane = tid & 63;
    const int w    = tid >> 6;        // wave 0..1
    const int o    = lane & 31;
    const int jh   = lane >> 5;

    const int is   = blockIdx.x & (ISTR - 1);  // same-W blocks are 128 apart
    const int bg   = blockIdx.x >> 7;          // -> land on the same XCD
    const int bblk = bg * BPB;

    const float4* wq = (const float4*)Wg;

    // v-sum fragments for this wave's 8 b's, held across the i-loop
    float4 va[8], vb[8];
    if (!FIRST) {
#pragma unroll
        for (int n = 0; n < 8; ++n) {
            const float* vp =
                vs + (size_t)(bblk + w * 8 + n) * (OC * OD) + o * OD + jh * 8;
            va[n] = ((const float4*)vp)[0];
            vb[n] = ((const float4*)vp)[1];
        }
    }

    float acc[8][8];
#pragma unroll
    for (int n = 0; n < 8; ++n)
#pragma unroll
        for (int jj = 0; jj < 8; ++jj) acc[n][jj] = 0.0f;

    // ---- prologue: stage tile 0 into parity 0
    {
        const int ig = is * IB;
        const size_t wb0 = (size_t)ig * 1024;
#pragma unroll
        for (int s = 0; s < 8; ++s) {
            const int D = s * 128 + tid;
            const int orow = D >> 5;
            const int f = orow * 32 + ((D & 31) ^ orow);
            gll16(wq + wb0 + f, &Wl[0][D]);
        }
        if (tid < 32)
            xsh[0][tid] = ((const float4*)xg)
                [((size_t)(bblk + (tid >> 1)) * IC + ig) * 2 + (tid & 1)];
    }

    for (int il = 0; il < IB; ++il) {
        const int p = il & 1;
        __syncthreads();   // drains tile(il) loads; nobody reads parity p^1

        // issue next tile's async loads immediately (hide under compute)
        float4 gx = {};
        const bool more = (il + 1 < IB);
        if (more) {
            const int ig = is * IB + il + 1;
            const size_t wb0 = (size_t)ig * 1024;
#pragma unroll
            for (int s = 0; s < 8; ++s) {
                const int D = s * 128 + tid;
                const int orow = D >> 5;
                const int f = orow * 32 + ((D & 31) ^ orow);
                gll16(wq + wb0 + f, &Wl[p ^ 1][D]);
            }
            if (tid < 32)
                gx = ((const float4*)xg)
                    [((size_t)(bblk + (tid >> 1)) * IC + ig) * 2 + (tid & 1)];
        }

        // W fragment -> registers (16 conflict-free ds_read_b128)
        float4 wA[8], wB[8];
        const int row = o * 32;
#pragma unroll
        for (int jj = 0; jj < 8; ++jj) {
            const int ca = (jh * 16 + jj * 2) ^ o;   // dq=0 slot
            wA[jj] = Wl[p][row + ca];
            wB[jj] = Wl[p][row + (ca ^ 1)];          // dq=1 slot
        }

#pragma unroll
        for (int n = 0; n < 8; ++n) {
            const float4 xa = xsh[p][(w * 8 + n) * 2];
            const float4 xb = xsh[p][(w * 8 + n) * 2 + 1];
            float u[8];
#pragma unroll
            for (int jj = 0; jj < 8; ++jj) {
                float t = wA[jj].x * xa.x;
                t = fmaf(wA[jj].y, xa.y, t);
                t = fmaf(wA[jj].z, xa.z, t);
                t = fmaf(wA[jj].w, xa.w, t);
                t = fmaf(wB[jj].x, xb.x, t);
                t = fmaf(wB[jj].y, xb.y, t);
                t = fmaf(wB[jj].z, xb.z, t);
                t = fmaf(wB[jj].w, xb.w, t);
                u[jj] = t;
            }
            float cc;
            if (FIRST) {
                cc = 1.0f;  // softmax(0) = 1/32, folded into the store scale
            } else {
                float bp = u[0] * va[n].x;
                bp = fmaf(u[1], va[n].y, bp);
                bp = fmaf(u[2], va[n].z, bp);
                bp = fmaf(u[3], va[n].w, bp);
                bp = fmaf(u[4], vb[n].x, bp);
                bp = fmaf(u[5], vb[n].y, bp);
                bp = fmaf(u[6], vb[n].z, bp);
                bp = fmaf(u[7], vb[n].w, bp);
                bp += __shfl_xor(bp, 32);            // combine j-halves
                // no max-subtraction: |logit| tiny, exp safe in fp32
                const float e = __expf(bp);
                float t = dpp_add<0xB1>(e);          // quad_perm xor1
                t = dpp_add<0x4E>(t);                // quad_perm xor2
                t = dpp_add<0x124>(t);               // row_ror:4
                t = dpp_add<0x128>(t);               // row_ror:8 -> row sum
                const float se = t + __shfl_xor(t, 16);  // 32-o total
                cc = e * __builtin_amdgcn_rcpf(se);
            }
#pragma unroll
            for (int jj = 0; jj < 8; ++jj)
                acc[n][jj] = fmaf(cc, u[jj], acc[n][jj]);
        }

        // x for next tile (race-free: overwritten parity was last read
        // before the barrier at the top of this iteration)
        if (more && tid < 32) xsh[p ^ 1][tid] = gx;
    }

    // disjoint per-(istripe, b) partials — no atomics, no memset needed
    const float scale = FIRST ? (1.0f / 32.0f) : 1.0f;
#pragma unroll
    for (int n = 0; n < 8; ++n) {
        float* dst = part + (size_t)is * S_ELEMS
                   + (size_t)(bblk + w * 8 + n) * (OC * OD) + o * OD + jh * 8;
        float4 lo = {acc[n][0] * scale, acc[n][1] * scale,
                     acc[n][2] * scale, acc[n][3] * scale};
        float4 hi = {acc[n][4] * scale, acc[n][5] * scale,
                     acc[n][6] * scale, acc[n][7] * scale};
        ((float4*)dst)[0] = lo;
        ((float4*)dst)[1] = hi;
    }
}

// Fused 128-way partial reduction + squash, 512 blocks (2/CU).
// Block handles 64 elems; wave w sums stripes k===w (mod 4), coalesced 256B
// wave-loads; 4-way LDS combine; squash over 16-j lane groups.
// MODE 0: vsum = v   MODE 1: vsum += v   MODE 2: out = v
template <int MODE>
__launch_bounds__(256, 4)
__global__ void caps_reduce(const float* __restrict__ part,
                            float* __restrict__ vsum,
                            float* __restrict__ out)
{
    __shared__ float red[4][64];
    const int tid  = threadIdx.x;
    const int w    = tid >> 6;
    const int lane = tid & 63;
    const int e0   = blockIdx.x * 64;

    float s = 0.0f;
#pragma unroll 8
    for (int k = w; k < ISTR; k += 4)
        s += part[(size_t)k * S_ELEMS + e0 + lane];
    red[w][lane] = s;
    __syncthreads();

    if (tid < 64) {
        const float t = red[0][tid] + red[1][tid] + red[2][tid] + red[3][tid];
        float s2 = t * t;               // ||s||^2 over the 16 j's
        s2 += __shfl_xor(s2, 1);
        s2 += __shfl_xor(s2, 2);
        s2 += __shfl_xor(s2, 4);
        s2 += __shfl_xor(s2, 8);
        const float v = t * (s2 / ((1.0f + s2) * sqrtf(s2 + 1e-9f)));
        const int e = e0 + tid;
        if (MODE == 0)      vsum[e] = v;
        else if (MODE == 1) vsum[e] += v;
        else                out[e] = v;
    }
}

extern "C" void kernel_launch(void* const* d_in, const int* in_sizes, int n_in,
                              void* d_out, int out_size, void* d_ws, size_t ws_size,
                              hipStream_t stream)
{
    const float* x = (const float*)d_in[0];   // [64, 2048, 8]
    const float* W = (const float*)d_in[1];   // [1, 2048, 32, 16, 8]
    float* out = (float*)d_out;               // [64, 32, 16]

    float* part = (float*)d_ws;                        // 128 x 32768 = 16 MB
    float* vsum = part + (size_t)ISTR * S_ELEMS;       // 32768 floats

    const dim3 gP(BG * ISTR);     // 512 blocks
    const dim3 bP(128);
    const dim3 gR(S_ELEMS / 64);  // 512 blocks
    const dim3 bR(256);

    // round 0: c uniform
    caps_pass<1><<<gP, bP, 0, stream>>>(W, x, nullptr, part);
    caps_reduce<0><<<gR, bR, 0, stream>>>(part, vsum, out);   // vsum = v0
    // round 1: b = u.v0
    caps_pass<0><<<gP, bP, 0, stream>>>(W, x, vsum, part);
    caps_reduce<1><<<gR, bR, 0, stream>>>(part, vsum, out);   // vsum = v0+v1
    // round 2: b = u.(v0+v1)
    caps_pass<0><<<gP, bP, 0, stream>>>(W, x, vsum, part);
    caps_reduce<2><<<gR, bR, 0, stream>>>(part, vsum, out);   // out = v2
}